// Round 5
// baseline (242.637 us; speedup 1.0000x reference)
//
#include <hip/hip_runtime.h>
#include <hip/hip_bf16.h>
#include <stdint.h>
#include <stddef.h>

// DistanceNetwork: sims[n,b] = dot(support[n], input[b]) * rsqrt(||support[n]||^2) * rsqrt(||input||_F^2)
//   support_set: [8192, 1024] fp32   input_image: [2048, 1024] fp32   out: [8192, 2048] fp32
#define M_DIM 8192
#define N_DIM 2048
#define K_DIM 1024

#define BM 128
#define BN 128
#define BK 64

typedef __attribute__((ext_vector_type(8))) short short8;   // 8 bf16 = 4 VGPRs
typedef __attribute__((ext_vector_type(4))) float float4v;  // MFMA C/D

// fp32 -> bf16 RNE
static __device__ __forceinline__ unsigned short f2bf(float x) {
  union { float f; unsigned u; } c; c.f = x;
  return (unsigned short)((c.u + 0x7FFFu + ((c.u >> 16) & 1u)) >> 16);
}

// ---------------- fused prep ----------------
__global__ __launch_bounds__(256) void prep(
    const float* __restrict__ S, const float* __restrict__ I,
    unsigned short* __restrict__ Sb, unsigned short* __restrict__ Ib,
    float* __restrict__ smag, float* __restrict__ partials) {
  const int t = threadIdx.x;
  const int blk = blockIdx.x;
  const bool isS = blk < M_DIM;
  const int row = isS ? blk : blk - M_DIM;
  const float* src = (isS ? S : I) + (size_t)row * K_DIM;
  unsigned short* dst = (isS ? Sb : Ib) + (size_t)row * K_DIM;

  const float4 v = reinterpret_cast<const float4*>(src)[t];
  ushort4 b;
  b.x = f2bf(v.x); b.y = f2bf(v.y); b.z = f2bf(v.z); b.w = f2bf(v.w);
  reinterpret_cast<ushort4*>(dst)[t] = b;

  float ss = v.x * v.x + v.y * v.y + v.z * v.z + v.w * v.w;
#pragma unroll
  for (int m = 32; m >= 1; m >>= 1) ss += __shfl_xor(ss, m, 64);
  __shared__ float wsum[4];
  if ((t & 63) == 0) wsum[t >> 6] = ss;
  __syncthreads();
  if (t == 0) {
    const float tot = wsum[0] + wsum[1] + wsum[2] + wsum[3];
    if (isS) smag[row] = rsqrtf(fmaxf(tot, 1e-10f));
    else     partials[row] = tot;
  }
}

// ---------------- GEMM ----------------
// R2/R3's verified-zero-conflict XOR-swizzled LDS layout (position p holds
// global chunk (row=p>>3, kc=(p&7)^((p>>3)&7)); writes lane-consecutive
// 16B/lane), but staged through REGISTERS: loads issued at top of iter,
// ds_write at bottom AFTER the MFMAs. In-flight VMEM at the barriers are
// pure loads (no LDS-write obligation), so the barrier needs only lgkmcnt —
// the m97-structure vmcnt(0) drain (global_load_lds's ~20% stall) is gone.
__global__ __launch_bounds__(256) void gemm_bt(
    const unsigned short* __restrict__ A,  // [M, K] bf16 (support)
    const unsigned short* __restrict__ B,  // [N, K] bf16 (input)
    const float* __restrict__ smag,        // [M]
    const float* __restrict__ partials,    // [2048] input-row sumsq partials
    float* __restrict__ C) {               // [M, N]
  __shared__ unsigned short lA[BM * BK];   // 16 KB
  __shared__ unsigned short lB[BN * BK];   // 16 KB -> ~33 KB total, 4 blocks/CU by LDS
  __shared__ float wsum[4];

  const int t = threadIdx.x;
  const int lane = t & 63;
  const int wave = t >> 6;
  const int wr = wave >> 1;  // wave row 0..1
  const int wc = wave & 1;   // wave col 0..1

  // XCD-aware swizzle (R3: halved FETCH_SIZE).
  const int blk = blockIdx.x;
  const int xcd = blk & 7;
  const int slot = blk >> 3;
  const int bn = (slot >> 3) * BN;
  const int bm = (xcd * 8 + (slot & 7)) * BM;

  // Input-magnitude reduction, visible after first barrier.
  {
    float p = 0.f;
#pragma unroll
    for (int i = 0; i < 2048 / 256; ++i) p += partials[t + i * 256];
#pragma unroll
    for (int m = 32; m >= 1; m >>= 1) p += __shfl_xor(p, m, 64);
    if ((t & 63) == 0) wsum[t >> 6] = p;
  }

  // Staging: thread t owns LDS positions p = t + 256*i (i=0..3) per matrix.
  //   write byte addr = 16*(t+256i)  -> lane-consecutive, conflict-free.
  //   global chunk at p: row = p>>3 = (t>>3)+32i, kc = (t&7)^((t>>3)&7) (i-invariant).
  const int kcg = (t & 7) ^ ((t >> 3) & 7);
  const int r0 = t >> 3;
  const unsigned short* gA[4];
  const unsigned short* gB[4];
#pragma unroll
  for (int i = 0; i < 4; ++i) {
    gA[i] = A + (size_t)(bm + r0 + 32 * i) * K_DIM + kcg * 8;
    gB[i] = B + (size_t)(bn + r0 + 32 * i) * K_DIM + kcg * 8;
  }
  unsigned short* wAp = lA + (size_t)t * 8;  // +256i*8 shorts per i
  unsigned short* wBp = lB + (size_t)t * 8;

  // Fragment reads (verified 0-conflict): A[m=lane&15][k=(lane>>4)*8+j],
  // swizzled column pc = ((4s+q)^(fr&7))*8.
  const int fr = lane & 15;
  const int q = lane >> 4;
  const unsigned short* rA = lA + (wr * 64 + fr) * BK;
  const unsigned short* rB = lB + (wc * 64 + fr) * BK;
  const int sw = fr & 7;

  float4v acc[4][4];
#pragma unroll
  for (int i = 0; i < 4; ++i)
#pragma unroll
    for (int j = 0; j < 4; ++j) acc[i][j] = (float4v)0.0f;

  // Prologue: stage slab 0.
  uint4 sa[4], sb[4];
#pragma unroll
  for (int i = 0; i < 4; ++i) {
    sa[i] = *reinterpret_cast<const uint4*>(gA[i]);
    sb[i] = *reinterpret_cast<const uint4*>(gB[i]);
    gA[i] += BK; gB[i] += BK;
  }
#pragma unroll
  for (int i = 0; i < 4; ++i) {
    *reinterpret_cast<uint4*>(wAp + i * 2048) = sa[i];  // 256 chunks * 8 shorts
    *reinterpret_cast<uint4*>(wBp + i * 2048) = sb[i];
  }

  for (int kt = 0; kt < K_DIM / BK; ++kt) {
    __syncthreads();  // publish slab kt (lgkm drain only — no vmcnt obligation)

    // k-step 0 frag reads
    short8 af0[4], bf0[4];
#pragma unroll
    for (int i = 0; i < 4; ++i)
      af0[i] = *reinterpret_cast<const short8*>(rA + i * 16 * BK + (q ^ sw) * 8);
#pragma unroll
    for (int j = 0; j < 4; ++j)
      bf0[j] = *reinterpret_cast<const short8*>(rB + j * 16 * BK + (q ^ sw) * 8);

    // issue next slab's loads — consumed only at the bottom ds_write,
    // after 32 MFMAs of latency cover.
    if (kt < K_DIM / BK - 1) {
#pragma unroll
      for (int i = 0; i < 4; ++i) {
        sa[i] = *reinterpret_cast<const uint4*>(gA[i]);
        sb[i] = *reinterpret_cast<const uint4*>(gB[i]);
        gA[i] += BK; gB[i] += BK;
      }
    }

#pragma unroll
    for (int i = 0; i < 4; ++i)
#pragma unroll
      for (int j = 0; j < 4; ++j)
        acc[i][j] = __builtin_amdgcn_mfma_f32_16x16x32_bf16(af0[i], bf0[j], acc[i][j], 0, 0, 0);

    // k-step 1 frag reads (overlap with s0 MFMAs) + MFMAs
    short8 af1[4], bf1[4];
#pragma unroll
    for (int i = 0; i < 4; ++i)
      af1[i] = *reinterpret_cast<const short8*>(rA + i * 16 * BK + ((4 + q) ^ sw) * 8);
#pragma unroll
    for (int j = 0; j < 4; ++j)
      bf1[j] = *reinterpret_cast<const short8*>(rB + j * 16 * BK + ((4 + q) ^ sw) * 8);
#pragma unroll
    for (int i = 0; i < 4; ++i)
#pragma unroll
      for (int j = 0; j < 4; ++j)
        acc[i][j] = __builtin_amdgcn_mfma_f32_16x16x32_bf16(af1[i], bf1[j], acc[i][j], 0, 0, 0);

    __syncthreads();  // slab kt fully consumed (lgkm only)

    if (kt < K_DIM / BK - 1) {  // vmcnt wait lands here — loads long complete
#pragma unroll
      for (int i = 0; i < 4; ++i) {
        *reinterpret_cast<uint4*>(wAp + i * 2048) = sa[i];
        *reinterpret_cast<uint4*>(wBp + i * 2048) = sb[i];
      }
    }
  }

  // Epilogue: C/D layout col = lane&15, row = (lane>>4)*4 + reg (proven)
  const float imag = rsqrtf(fmaxf(wsum[0] + wsum[1] + wsum[2] + wsum[3], 1e-10f));
#pragma unroll
  for (int i = 0; i < 4; ++i) {
    const int rbase = bm + wr * 64 + i * 16 + q * 4;
#pragma unroll
    for (int r = 0; r < 4; ++r) {
      const int row = rbase + r;
      const float s = smag[row] * imag;
      float* crow = C + (size_t)row * N_DIM + bn + wc * 64 + fr;
#pragma unroll
      for (int j = 0; j < 4; ++j) crow[j * 16] = acc[i][j][r] * s;
    }
  }
}

// ---------------- launch ----------------
extern "C" void kernel_launch(void* const* d_in, const int* in_sizes, int n_in,
                              void* d_out, int out_size, void* d_ws, size_t ws_size,
                              hipStream_t stream) {
  const float* S = (const float*)d_in[0];  // support_set [8192,1024]
  const float* I = (const float*)d_in[1];  // input_image [2048,1024]
  float* out = (float*)d_out;

  // ws layout: Sb bf16 16MB | Ib bf16 4MB | smag 32KB | partials 8KB
  unsigned char* ws = (unsigned char*)d_ws;
  unsigned short* Sb = (unsigned short*)ws;
  unsigned short* Ib = (unsigned short*)(ws + (size_t)M_DIM * K_DIM * 2);
  float* smag = (float*)(ws + (size_t)M_DIM * K_DIM * 2 + (size_t)N_DIM * K_DIM * 2);
  float* partials = smag + M_DIM;

  hipLaunchKernelGGL(prep, dim3(M_DIM + N_DIM), dim3(256), 0, stream,
                     S, I, Sb, Ib, smag, partials);
  hipLaunchKernelGGL(gemm_bt, dim3((M_DIM / BM) * (N_DIM / BN)), dim3(256), 0, stream,
                     Sb, Ib, smag, partials, out);
}

// Round 6
// 141.576 us; speedup vs baseline: 1.7138x; 1.7138x over previous
//
#include <hip/hip_runtime.h>
#include <hip/hip_bf16.h>
#include <stdint.h>
#include <stddef.h>

// DistanceNetwork: sims[n,b] = dot(support[n], input[b]) * rsqrt(||support[n]||^2) * rsqrt(||input||_F^2)
//   support_set: [8192, 1024] fp32   input_image: [2048, 1024] fp32   out: [8192, 2048] fp32
#define M_DIM 8192
#define N_DIM 2048
#define K_DIM 1024

#define BM 128
#define BN 128
#define BK 32   // one 16x16x32 k-step per slab; 4 chunks(16B) per row

typedef __attribute__((ext_vector_type(8))) short short8;   // 8 bf16 = 4 VGPRs
typedef __attribute__((ext_vector_type(4))) float float4v;  // MFMA C/D

// fp32 -> bf16 RNE
static __device__ __forceinline__ unsigned short f2bf(float x) {
  union { float f; unsigned u; } c; c.f = x;
  return (unsigned short)((c.u + 0x7FFFu + ((c.u >> 16) & 1u)) >> 16);
}

// ---------------- fused prep ----------------
__global__ __launch_bounds__(256) void prep(
    const float* __restrict__ S, const float* __restrict__ I,
    unsigned short* __restrict__ Sb, unsigned short* __restrict__ Ib,
    float* __restrict__ smag, float* __restrict__ partials) {
  const int t = threadIdx.x;
  const int blk = blockIdx.x;
  const bool isS = blk < M_DIM;
  const int row = isS ? blk : blk - M_DIM;
  const float* src = (isS ? S : I) + (size_t)row * K_DIM;
  unsigned short* dst = (isS ? Sb : Ib) + (size_t)row * K_DIM;

  const float4 v = reinterpret_cast<const float4*>(src)[t];
  ushort4 b;
  b.x = f2bf(v.x); b.y = f2bf(v.y); b.z = f2bf(v.z); b.w = f2bf(v.w);
  reinterpret_cast<ushort4*>(dst)[t] = b;

  float ss = v.x * v.x + v.y * v.y + v.z * v.z + v.w * v.w;
#pragma unroll
  for (int m = 32; m >= 1; m >>= 1) ss += __shfl_xor(ss, m, 64);
  __shared__ float wsum[4];
  if ((t & 63) == 0) wsum[t >> 6] = ss;
  __syncthreads();
  if (t == 0) {
    const float tot = wsum[0] + wsum[1] + wsum[2] + wsum[3];
    if (isS) smag[row] = rsqrtf(fmaxf(tot, 1e-10f));
    else     partials[row] = tot;
  }
}

// ---------------- GEMM ----------------
// BK=32 double-buffered, register-staged, ONE barrier per slab.
//  - R4 proved 16 held staging regs don't spill (VGPR 92); R5's 32 did
//    (337MB scratch). Here: 4 x uint4 = 16.
//  - Both LDS sides are dense permutations of contiguous regions:
//    writes = 16B/lane lane-consecutive (R2/R3-measured 0-conflict);
//    reads  = each b128 covers a contiguous 1KB region exactly once.
//  - In-flight VMEM at the barrier are pure loads (no LDS-write obligation),
//    so no vmcnt(0) drain; ds_write at the bottom is covered by 16 MFMAs.
__global__ __launch_bounds__(256) void gemm_bt(
    const unsigned short* __restrict__ A,  // [M, K] bf16 (support)
    const unsigned short* __restrict__ B,  // [N, K] bf16 (input)
    const float* __restrict__ smag,        // [M]
    const float* __restrict__ partials,    // [2048] input-row sumsq partials
    float* __restrict__ C) {               // [M, N]
  __shared__ unsigned short lA[2][BM * BK];  // 2 x 8 KB
  __shared__ unsigned short lB[2][BN * BK];  // 2 x 8 KB  -> 32 KB total
  __shared__ float wsum[4];

  const int t = threadIdx.x;
  const int lane = t & 63;
  const int wave = t >> 6;
  const int wr = wave >> 1;  // wave row 0..1
  const int wc = wave & 1;   // wave col 0..1

  // XCD-aware swizzle (R3: halved FETCH_SIZE).
  const int blk = blockIdx.x;
  const int xcd = blk & 7;
  const int slot = blk >> 3;
  const int bn = (slot >> 3) * BN;
  const int bm = (xcd * 8 + (slot & 7)) * BM;

  // Input-magnitude reduction, visible after first barrier.
  {
    float p = 0.f;
#pragma unroll
    for (int i = 0; i < 2048 / 256; ++i) p += partials[t + i * 256];
#pragma unroll
    for (int m = 32; m >= 1; m >>= 1) p += __shfl_xor(p, m, 64);
    if ((t & 63) == 0) wsum[t >> 6] = p;
  }

  // Staging map: per matrix per slab, 512 chunk positions (128 rows x 4).
  // Thread t owns p = t (rows 0..63) and p = t+256 (rows 64..127).
  // Position p holds global (row = p>>2, kc = (p&3) ^ ((p>>2)&3)).
  const int r0 = t >> 2;
  const int kcg = (t & 3) ^ (r0 & 3);   // invariant under row+64
  const unsigned short* gA0 = A + (size_t)(bm + r0) * K_DIM + kcg * 8;
  const unsigned short* gA1 = A + (size_t)(bm + r0 + 64) * K_DIM + kcg * 8;
  const unsigned short* gB0 = B + (size_t)(bn + r0) * K_DIM + kcg * 8;
  const unsigned short* gB1 = B + (size_t)(bn + r0 + 64) * K_DIM + kcg * 8;
  const int w0 = t * 8;          // LDS write offset in shorts (byte 16t)
  const int w1 = t * 8 + 2048;   // byte 16t + 4096

  // Frag reads: A[m = lane&15][k = (lane>>4)*8 + j]; physical chunk q^(fr&3).
  const int fr = lane & 15;
  const int q = lane >> 4;       // 0..3 = k-chunk
  const int rAo = (wr * 64 + fr) * BK + (q ^ (fr & 3)) * 8;
  const int rBo = (wc * 64 + fr) * BK + (q ^ (fr & 3)) * 8;

  float4v acc[4][4];
#pragma unroll
  for (int i = 0; i < 4; ++i)
#pragma unroll
    for (int j = 0; j < 4; ++j) acc[i][j] = (float4v)0.0f;

  // Prologue: stage slab 0 into buf 0.
  uint4 sa0 = *reinterpret_cast<const uint4*>(gA0);
  uint4 sa1 = *reinterpret_cast<const uint4*>(gA1);
  uint4 sb0 = *reinterpret_cast<const uint4*>(gB0);
  uint4 sb1 = *reinterpret_cast<const uint4*>(gB1);
  gA0 += BK; gA1 += BK; gB0 += BK; gB1 += BK;
  *reinterpret_cast<uint4*>(&lA[0][w0]) = sa0;
  *reinterpret_cast<uint4*>(&lA[0][w1]) = sa1;
  *reinterpret_cast<uint4*>(&lB[0][w0]) = sb0;
  *reinterpret_cast<uint4*>(&lB[0][w1]) = sb1;

#pragma unroll 2
  for (int kt = 0; kt < K_DIM / BK; ++kt) {
    __syncthreads();  // publish buf p (lgkm only; no vmcnt obligation)
    const int p = kt & 1;

    if (kt < K_DIM / BK - 1) {  // next slab's loads: issue earliest
      sa0 = *reinterpret_cast<const uint4*>(gA0);
      sa1 = *reinterpret_cast<const uint4*>(gA1);
      sb0 = *reinterpret_cast<const uint4*>(gB0);
      sb1 = *reinterpret_cast<const uint4*>(gB1);
      gA0 += BK; gA1 += BK; gB0 += BK; gB1 += BK;
    }

    short8 af[4], bf[4];
#pragma unroll
    for (int i = 0; i < 4; ++i)
      af[i] = *reinterpret_cast<const short8*>(&lA[p][rAo + i * 16 * BK]);
#pragma unroll
    for (int j = 0; j < 4; ++j)
      bf[j] = *reinterpret_cast<const short8*>(&lB[p][rBo + j * 16 * BK]);
#pragma unroll
    for (int i = 0; i < 4; ++i)
#pragma unroll
      for (int j = 0; j < 4; ++j)
        acc[i][j] = __builtin_amdgcn_mfma_f32_16x16x32_bf16(af[i], bf[j], acc[i][j], 0, 0, 0);

    if (kt < K_DIM / BK - 1) {  // vmcnt wait lands here, covered by the MFMAs
      *reinterpret_cast<uint4*>(&lA[p ^ 1][w0]) = sa0;
      *reinterpret_cast<uint4*>(&lA[p ^ 1][w1]) = sa1;
      *reinterpret_cast<uint4*>(&lB[p ^ 1][w0]) = sb0;
      *reinterpret_cast<uint4*>(&lB[p ^ 1][w1]) = sb1;
    }
  }

  // Epilogue: C/D layout col = lane&15, row = (lane>>4)*4 + reg (proven)
  const float imag = rsqrtf(fmaxf(wsum[0] + wsum[1] + wsum[2] + wsum[3], 1e-10f));
#pragma unroll
  for (int i = 0; i < 4; ++i) {
    const int rbase = bm + wr * 64 + i * 16 + q * 4;
#pragma unroll
    for (int r = 0; r < 4; ++r) {
      const int row = rbase + r;
      const float s = smag[row] * imag;
      float* crow = C + (size_t)row * N_DIM + bn + wc * 64 + fr;
#pragma unroll
      for (int j = 0; j < 4; ++j) crow[j * 16] = acc[i][j][r] * s;
    }
  }
}

// ---------------- launch ----------------
extern "C" void kernel_launch(void* const* d_in, const int* in_sizes, int n_in,
                              void* d_out, int out_size, void* d_ws, size_t ws_size,
                              hipStream_t stream) {
  const float* S = (const float*)d_in[0];  // support_set [8192,1024]
  const float* I = (const float*)d_in[1];  // input_image [2048,1024]
  float* out = (float*)d_out;

  // ws layout: Sb bf16 16MB | Ib bf16 4MB | smag 32KB | partials 8KB
  unsigned char* ws = (unsigned char*)d_ws;
  unsigned short* Sb = (unsigned short*)ws;
  unsigned short* Ib = (unsigned short*)(ws + (size_t)M_DIM * K_DIM * 2);
  float* smag = (float*)(ws + (size_t)M_DIM * K_DIM * 2 + (size_t)N_DIM * K_DIM * 2);
  float* partials = smag + M_DIM;

  hipLaunchKernelGGL(prep, dim3(M_DIM + N_DIM), dim3(256), 0, stream,
                     S, I, Sb, Ib, smag, partials);
  hipLaunchKernelGGL(gemm_bt, dim3((M_DIM / BM) * (N_DIM / BN)), dim3(256), 0, stream,
                     Sb, Ib, smag, partials, out);
}